// Round 10
// baseline (524.831 us; speedup 1.0000x reference)
//
#include <hip/hip_runtime.h>
#include <math.h>

#define HH 16
#define SS 2048
#define DD 128
#define NROWS (HH * SS)            // 32768
#define OUTSZ (HH * SS * DD)       // 4194304 elems per tensor

typedef __attribute__((ext_vector_type(8))) short bf16x8;
typedef __attribute__((ext_vector_type(4))) float f32x4;
typedef __attribute__((ext_vector_type(8))) unsigned short u16x8;

#define MFMA16(a, b, c) __builtin_amdgcn_mfma_f32_16x16x32_bf16(a, b, c, 0, 0, 0)

__device__ __forceinline__ unsigned short f2bf(float f) {
    unsigned u = __float_as_uint(f);
    return (unsigned short)((u + 0x7FFFu + ((u >> 16) & 1u)) >> 16);   // RNE
}
__device__ __forceinline__ bf16x8 negf(bf16x8 a) {
    bf16x8 r;
#pragma unroll
    for (int j = 0; j < 8; ++j) r[j] = (short)(a[j] ^ (short)0x8000);
    return r;
}

// ---------------------------------------------------------------------------
// conv6: fp32 -> bf16 for the 6 attention inputs (q,k,v x r,i). Pure
// streaming: 524288 groups of 8; each thread does one group per tensor.
// Rounding here == the f2bf previously applied at fragment build, so
// numerics are unchanged.
// ---------------------------------------------------------------------------
__global__ __launch_bounds__(256)
void conv6(const float* __restrict__ s0, const float* __restrict__ s1,
           const float* __restrict__ s2, const float* __restrict__ s3,
           const float* __restrict__ s4, const float* __restrict__ s5,
           unsigned short* __restrict__ d0, unsigned short* __restrict__ d1,
           unsigned short* __restrict__ d2, unsigned short* __restrict__ d3,
           unsigned short* __restrict__ d4, unsigned short* __restrict__ d5) {
    const long o = ((long)blockIdx.x * 256 + threadIdx.x) * 8;
    const float* ss[6] = {s0, s1, s2, s3, s4, s5};
    unsigned short* dd[6] = {d0, d1, d2, d3, d4, d5};
#pragma unroll
    for (int u = 0; u < 6; ++u) {
        const float4 a = *(const float4*)(ss[u] + o);
        const float4 b = *(const float4*)(ss[u] + o + 4);
        unsigned short tmp[8] = {f2bf(a.x), f2bf(a.y), f2bf(a.z), f2bf(a.w),
                                 f2bf(b.x), f2bf(b.y), f2bf(b.z), f2bf(b.w)};
        *(u16x8*)(dd[u] + o) = *(u16x8*)tmp;
    }
}

struct ClinBF {
    const unsigned short* xr; const unsigned short* xi;   // bf16 A
    const float* wr; const float* wi;                     // fp32 W (staged)
    const float* br; const float* bi;
    const float* per; const float* pei;                   // may be null
    void* yr; void* yi;
    int outbf;                                            // 1 bf16, 0 fp32
};

// ---------------------------------------------------------------------------
// R10 clin: bf16-A column-split worker. 512 thr = 8 waves, 128 rows x 64
// output cols (blockIdx.z), TILES row-tiles per block, W-half (34.8 KB)
// staged once. A-loads are single u16x8 per (dk,comp) -- the exact attn
// Q-fragment pattern the compiler pipelines well -- with whole-next-tile
// prefetch (fA/fB, 64 VGPR). No f32->bf16 convert in the loop (conv6 did
// it). R9 proved 2 blocks/CU co-schedule at this LDS; cur/nxt + 32 acc +
// misc ~ 120 VGPR fits the launch_bounds(512,4) 128 cap.
// ---------------------------------------------------------------------------
template <int TILES>
__global__ __launch_bounds__(512, 4)
void clin_bf(ClinBF P0, ClinBF P1, ClinBF P2, ClinBF P3) {
    __shared__ unsigned short wsh[2][64][136];   // 34816 B

    const int py = blockIdx.y;
    const ClinBF P = (py == 0) ? P0 : (py == 1) ? P1 : (py == 2) ? P2 : P3;

    const unsigned short* __restrict__ xr = P.xr;
    const unsigned short* __restrict__ xi = P.xi;
    const float* __restrict__ wr = P.wr;
    const float* __restrict__ wi = P.wi;
    const float* __restrict__ br = P.br;
    const float* __restrict__ bi = P.bi;
    const float* __restrict__ per = P.per;
    const float* __restrict__ pei = P.pei;

    const int t = threadIdx.x;
    const int w = t >> 6, lane = t & 63;
    const int lm = lane & 15, quad = lane >> 4;
    const int cb = blockIdx.z * 64;                   // output-col base
    const long rowA = (long)blockIdx.x * (128 * TILES);
    const long abase = (rowA + w * 16 + lm) * DD + quad * 8;

    // ---- prefetch tile-0 fragments (8 x u16x8) before W staging ----
    u16x8 fA[8], fB[8];
#pragma unroll
    for (int dk = 0; dk < 4; ++dk) {
        fA[dk]     = *(const u16x8*)(xr + abase + dk * 32);
        fA[4 + dk] = *(const u16x8*)(xi + abase + dk * 32);
    }

    // ---- stage W half fp32->bf16: 2048 groups of 8, 4 per thread ----
#pragma unroll
    for (int u = 0; u < 4; ++u) {
        const int f = t + 512 * u;
        const int c = f >> 10;
        const int rem = f & 1023;
        const int row = rem >> 4;
        const int g8 = (rem & 15) * 8;
        const float* src = (c ? wi : wr) + (long)(cb + row) * DD + g8;
        const float4 a = *(const float4*)src;
        const float4 b = *(const float4*)(src + 4);
        unsigned short tmp[8] = {f2bf(a.x), f2bf(a.y), f2bf(a.z), f2bf(a.w),
                                 f2bf(b.x), f2bf(b.y), f2bf(b.z), f2bf(b.w)};
        *(u16x8*)&wsh[c][row][g8] = *(u16x8*)tmp;
    }
    __syncthreads();

    const f32x4 z = {0.f, 0.f, 0.f, 0.f};

#pragma unroll
    for (int tt = 0; tt < TILES; ++tt) {
        u16x8* cur = (tt & 1) ? fB : fA;
        u16x8* nxt = (tt & 1) ? fA : fB;
        // ---- prefetch next tile's fragments ----
        if (tt + 1 < TILES) {
            const long o = abase + (long)(tt + 1) * 128 * DD;
#pragma unroll
            for (int dk = 0; dk < 4; ++dk) {
                nxt[dk]     = *(const u16x8*)(xr + o + dk * 32);
                nxt[4 + dk] = *(const u16x8*)(xi + o + dk * 32);
            }
        }

        f32x4 Or[4], Oi[4];
#pragma unroll
        for (int nt = 0; nt < 4; ++nt) { Or[nt] = z; Oi[nt] = z; }

#pragma unroll
        for (int dk = 0; dk < 4; ++dk) {
            const bf16x8 xrf = *(bf16x8*)&cur[dk];
            const bf16x8 xif = *(bf16x8*)&cur[4 + dk];
            const bf16x8 nxi = negf(xif);
            const int off = dk * 32 + quad * 8;
#pragma unroll
            for (int nt = 0; nt < 4; ++nt) {
                const bf16x8 wrf = *(bf16x8*)&wsh[0][nt * 16 + lm][off];
                const bf16x8 wif = *(bf16x8*)&wsh[1][nt * 16 + lm][off];
                Or[nt] = MFMA16(xrf, wrf, Or[nt]);
                Or[nt] = MFMA16(nxi, wif, Or[nt]);
                Oi[nt] = MFMA16(xrf, wif, Oi[nt]);
                Oi[nt] = MFMA16(xif, wrf, Oi[nt]);
            }
        }

        // ---- epilogue tile tt ----
        const long m0 = rowA + tt * 128 + w * 16;
#pragma unroll
        for (int nt = 0; nt < 4; ++nt) {
            const int c = cb + nt * 16 + lm;
            const float bra = br[c], bia = bi[c];
#pragma unroll
            for (int reg = 0; reg < 4; ++reg) {
                const long R = m0 + quad * 4 + reg;
                float vr = Or[nt][reg] + bra;
                float vi = Oi[nt][reg] + bia;
                if (per != nullptr) {
                    vr += per[R * DD + c];
                    vi += pei[R * DD + c];
                }
                if (P.outbf) {
                    ((unsigned short*)P.yr)[R * DD + c] = f2bf(vr);
                    ((unsigned short*)P.yi)[R * DD + c] = f2bf(vi);
                } else {
                    ((float*)P.yr)[R * DD + c] = vr;
                    ((float*)P.yi)[R * DD + c] = vi;
                }
            }
        }
    }
}

// ---------------------------------------------------------------------------
// MFMA flash attention (exact R3 loop, 130.7 us) + FUSED GATE EPILOGUE:
// a = O/l is in registers at the end; read g (fp32), compute ga = g (*) a,
// write bf16 to workspace. Kills the separate 67 MB fp32 gate-read path
// and halves the attn-output write (bf16 vs fp32).
// ---------------------------------------------------------------------------
__global__ __launch_bounds__(512, 2)
void attn_mfma(const unsigned short* __restrict__ qr, const unsigned short* __restrict__ qi,
               const unsigned short* __restrict__ kr, const unsigned short* __restrict__ ki,
               const unsigned short* __restrict__ vr, const unsigned short* __restrict__ vi,
               const float* __restrict__ g_r, const float* __restrict__ g_i,
               unsigned short* __restrict__ gar, unsigned short* __restrict__ gai) {
    __shared__ unsigned short ks[2][2][32][136];   // 34816 B
    __shared__ unsigned short vt[2][2][DD][40];    // 40960 B
    __shared__ unsigned short ps[128][40];         // 10240 B

    const int t = threadIdx.x;
    const int w = t >> 6, lane = t & 63;
    const int lm = lane & 15, quad = lane >> 4;

    const int bid = blockIdx.x;
    const int xcd = bid & 7;
    const int rr = bid >> 3;          // 0..31
    const int qt = rr & 15;
    const int h  = xcd + 8 * (rr >> 4);
    const long hbase = (long)h * SS * DD;
    const int q0 = qt * 128;
    const float scale = 0.08838834764831845f;   // 128^-0.5

    int kC[2], kR[2], kG[2];
    const unsigned short* kp[2];
#pragma unroll
    for (int u = 0; u < 2; ++u) {
        const int f = t + 512 * u;
        kC[u] = f >> 9;
        kR[u] = (f & 511) >> 4;
        kG[u] = (f & 15) * 8;
        kp[u] = (kC[u] ? ki : kr) + hbase + (long)kR[u] * DD + kG[u];
    }
    const int vC = t >> 8;
    const int vS2 = (t & 15) * 2;
    const int vD8 = ((t >> 4) & 15) * 8;
    const unsigned short* vp = (vC ? vi : vr) + hbase + (long)vS2 * DD + vD8;

    u16x8 kA0, kA1, vA0, vA1;
    kA0 = *(const u16x8*)(kp[0]);
    kA1 = *(const u16x8*)(kp[1]);
    vA0 = *(const u16x8*)(vp);
    vA1 = *(const u16x8*)(vp + DD);

    bf16x8 qrf[4], qif[4];
    {
        const long rb = hbase + (long)(q0 + w * 16 + lm) * DD;
#pragma unroll
        for (int dk = 0; dk < 4; ++dk) {
            qrf[dk] = *(const bf16x8*)(qr + rb + dk * 32 + quad * 8);
            qif[dk] = *(const bf16x8*)(qi + rb + dk * 32 + quad * 8);
        }
    }

    f32x4 Or[8], Oi[8];
    const f32x4 z = {0.f, 0.f, 0.f, 0.f};
#pragma unroll
    for (int nt = 0; nt < 8; ++nt) { Or[nt] = z; Oi[nt] = z; }
    float l_st[4] = {0.f, 0.f, 0.f, 0.f};

#pragma unroll
    for (int u = 0; u < 2; ++u)
        *(u16x8*)&ks[0][kC[u]][kR[u]][kG[u]] = (u ? kA1 : kA0);
#pragma unroll
    for (int j = 0; j < 8; ++j) {
        const unsigned val = (unsigned)(unsigned short)vA0[j] |
                             ((unsigned)(unsigned short)vA1[j] << 16);
        *(unsigned*)&vt[0][vC][vD8 + j][vS2] = val;
    }
    __syncthreads();

    for (int kt = 0; kt < SS / 32; ++kt) {
        const int b = kt & 1;
        if (kt + 1 < SS / 32) {
            const long koff = (long)(kt + 1) * 32 * DD;
            kA0 = *(const u16x8*)(kp[0] + koff);
            kA1 = *(const u16x8*)(kp[1] + koff);
            vA0 = *(const u16x8*)(vp + koff);
            vA1 = *(const u16x8*)(vp + koff + DD);
        }

        f32x4 sr0 = z, sr1 = z, si0 = z, si1 = z;
#pragma unroll
        for (int dk = 0; dk < 4; ++dk) {
            const int off = dk * 32 + quad * 8;
            const bf16x8 kr0 = *(bf16x8*)&ks[b][0][lm][off];
            const bf16x8 ki0 = *(bf16x8*)&ks[b][1][lm][off];
            const bf16x8 kr1 = *(bf16x8*)&ks[b][0][16 + lm][off];
            const bf16x8 ki1 = *(bf16x8*)&ks[b][1][16 + lm][off];
            const bf16x8 nq = negf(qrf[dk]);
            sr0 = MFMA16(qrf[dk], kr0, sr0);  sr0 = MFMA16(qif[dk], ki0, sr0);
            si0 = MFMA16(qif[dk], kr0, si0);  si0 = MFMA16(nq, ki0, si0);
            sr1 = MFMA16(qrf[dk], kr1, sr1);  sr1 = MFMA16(qif[dk], ki1, sr1);
            si1 = MFMA16(qif[dk], kr1, si1);  si1 = MFMA16(nq, ki1, si1);
        }

#pragma unroll
        for (int reg = 0; reg < 4; ++reg) {
            const float s0 = __builtin_amdgcn_sqrtf(
                fmaf(sr0[reg], sr0[reg], fmaf(si0[reg], si0[reg], 1e-8f))) * scale;
            const float s1 = __builtin_amdgcn_sqrtf(
                fmaf(sr1[reg], sr1[reg], fmaf(si1[reg], si1[reg], 1e-8f))) * scale;
            const float p0 = __expf(s0);
            const float p1 = __expf(s1);
            l_st[reg] += p0 + p1;
            ps[w * 16 + quad * 4 + reg][lm]      = f2bf(p0);
            ps[w * 16 + quad * 4 + reg][16 + lm] = f2bf(p1);
        }

        const bf16x8 pf = *(bf16x8*)&ps[w * 16 + lm][quad * 8];
#pragma unroll
        for (int nt = 0; nt < 8; ++nt) {
            const bf16x8 vrf = *(bf16x8*)&vt[b][0][nt * 16 + lm][quad * 8];
            const bf16x8 vif = *(bf16x8*)&vt[b][1][nt * 16 + lm][quad * 8];
            Or[nt] = MFMA16(pf, vrf, Or[nt]);
            Oi[nt] = MFMA16(pf, vif, Oi[nt]);
        }

        if (kt + 1 < SS / 32) {
            __syncthreads();
#pragma unroll
            for (int u = 0; u < 2; ++u)
                *(u16x8*)&ks[b ^ 1][kC[u]][kR[u]][kG[u]] = (u ? kA1 : kA0);
#pragma unroll
            for (int j = 0; j < 8; ++j) {
                const unsigned val = (unsigned)(unsigned short)vA0[j] |
                                     ((unsigned)(unsigned short)vA1[j] << 16);
                *(unsigned*)&vt[b ^ 1][vC][vD8 + j][vS2] = val;
            }
            __syncthreads();
        }
    }

    // ---- finalize + fused gate: ga = g (*) (O / l), bf16 out ----
    float linv[4];
#pragma unroll
    for (int reg = 0; reg < 4; ++reg) {
        float l = l_st[reg];
#pragma unroll
        for (int off = 1; off < 16; off <<= 1) l += __shfl_xor(l, off);
        linv[reg] = 1.f / l;
    }
    const long ob = hbase + (long)(q0 + w * 16) * DD;
#pragma unroll
    for (int nt = 0; nt < 8; ++nt) {
        const int c = nt * 16 + lm;
#pragma unroll
        for (int reg = 0; reg < 4; ++reg) {
            const long R = ob + (long)(quad * 4 + reg) * DD + c;
            const float ar = Or[nt][reg] * linv[reg];
            const float ai = Oi[nt][reg] * linv[reg];
            const float g1 = g_r[R];
            const float g2 = g_i[R];
            gar[R] = f2bf(g1 * ar - g2 * ai);
            gai[R] = f2bf(g1 * ai + g2 * ar);
        }
    }
}

// ---------------------------------------------------------------------------
extern "C" void kernel_launch(void* const* d_in, const int* in_sizes, int n_in,
                              void* d_out, int out_size, void* d_ws, size_t ws_size,
                              hipStream_t stream) {
    const float* q_r    = (const float*)d_in[0];
    const float* q_i    = (const float*)d_in[1];
    const float* k_r    = (const float*)d_in[2];
    const float* k_i    = (const float*)d_in[3];
    const float* v_r    = (const float*)d_in[4];
    const float* v_i    = (const float*)d_in[5];
    const float* pe_q_r = (const float*)d_in[6];
    const float* pe_q_i = (const float*)d_in[7];
    const float* pe_k_r = (const float*)d_in[8];
    const float* pe_k_i = (const float*)d_in[9];
    const float* qw_r = (const float*)d_in[10];
    const float* qw_i = (const float*)d_in[11];
    const float* qb_r = (const float*)d_in[12];
    const float* qb_i = (const float*)d_in[13];
    const float* kw_r = (const float*)d_in[14];
    const float* kw_i = (const float*)d_in[15];
    const float* kb_r = (const float*)d_in[16];
    const float* kb_i = (const float*)d_in[17];
    const float* vw_r = (const float*)d_in[18];
    const float* vw_i = (const float*)d_in[19];
    const float* vb_r = (const float*)d_in[20];
    const float* vb_i = (const float*)d_in[21];
    const float* gw_r = (const float*)d_in[22];
    const float* gw_i = (const float*)d_in[23];
    const float* gb_r = (const float*)d_in[24];
    const float* gb_i = (const float*)d_in[25];
    const float* ow_r = (const float*)d_in[26];
    const float* ow_i = (const float*)d_in[27];
    const float* ob_r = (const float*)d_in[28];
    const float* ob_i = (const float*)d_in[29];

    float* out_r = (float*)d_out;              // scratch (conv q), then final
    float* out_i = out_r + (long)OUTSZ;        // scratch (conv k), then final
    float* g_r   = out_r + 2L * OUTSZ;         // final gate outputs
    float* g_i   = out_r + 3L * OUTSZ;
    unsigned short* d0u = (unsigned short*)d_out;   // slots 0,1 as bf16 scratch

    unsigned short* ws = (unsigned short*)d_ws;     // 10 x OUTSZ bf16 = 80 MiB
    unsigned short* pqr = ws + 0L * OUTSZ;          // proj outputs
    unsigned short* pqi = ws + 1L * OUTSZ;
    unsigned short* pkr = ws + 2L * OUTSZ;
    unsigned short* pki = ws + 3L * OUTSZ;
    unsigned short* pvr = ws + 4L * OUTSZ;
    unsigned short* pvi = ws + 5L * OUTSZ;
    unsigned short* cvr = ws + 6L * OUTSZ;          // conv v bf16
    unsigned short* cvi = ws + 7L * OUTSZ;
    unsigned short* gar = ws + 8L * OUTSZ;          // gated attn bf16
    unsigned short* gai = ws + 9L * OUTSZ;
    // conv q,k bf16 live in d_out slots 0,1 (dead before final proj writes)
    unsigned short* cqr = d0u + 0L * OUTSZ;
    unsigned short* cqi = d0u + 1L * OUTSZ;
    unsigned short* ckr = d0u + 2L * OUTSZ;
    unsigned short* cki = d0u + 3L * OUTSZ;

    // 1. convert x -> bf16 (rounding identical to old fragment-build f2bf)
    conv6<<<dim3(OUTSZ / 8 / 256), dim3(256), 0, stream>>>(
        q_r, q_i, k_r, k_i, v_r, v_i, cqr, cqi, ckr, cki, cvr, cvi);

    // 2. four projections (q,k,v,gate), bf16 A, col-split, 4 tiles/block:
    //    grid (64,4,2) = 512 blocks = 2 resident blocks/CU
    ClinBF P0 = {cqr, cqi, qw_r, qw_i, qb_r, qb_i, pe_q_r, pe_q_i, pqr, pqi, 1};
    ClinBF P1 = {ckr, cki, kw_r, kw_i, kb_r, kb_i, pe_k_r, pe_k_i, pkr, pki, 1};
    ClinBF P2 = {cvr, cvi, vw_r, vw_i, vb_r, vb_i, nullptr, nullptr, pvr, pvi, 1};
    ClinBF P3 = {cqr, cqi, gw_r, gw_i, gb_r, gb_i, nullptr, nullptr, g_r, g_i, 0};
    clin_bf<4><<<dim3(64, 4, 2), dim3(512), 0, stream>>>(P0, P1, P2, P3);

    // 3. flash attention with fused gate epilogue -> ga (bf16, ws)
    attn_mfma<<<dim3((SS / 128) * HH), dim3(512), 0, stream>>>(
        pqr, pqi, pkr, pki, pvr, pvi, g_r, g_i, gar, gai);

    // 4. final o-projection: plain bf16 clin, fp32 out into d_out slots 0,1
    ClinBF PF = {gar, gai, ow_r, ow_i, ob_r, ob_i, nullptr, nullptr,
                 out_r, out_i, 0};
    clin_bf<1><<<dim3(256, 1, 2), dim3(512), 0, stream>>>(PF, PF, PF, PF);
}

// Round 11
// 419.647 us; speedup vs baseline: 1.2506x; 1.2506x over previous
//
#include <hip/hip_runtime.h>
#include <math.h>

#define HH 16
#define SS 2048
#define DD 128
#define NROWS (HH * SS)            // 32768
#define OUTSZ (HH * SS * DD)       // 4194304 elems per tensor

typedef __attribute__((ext_vector_type(8))) short bf16x8;
typedef __attribute__((ext_vector_type(4))) float f32x4;
typedef __attribute__((ext_vector_type(8))) unsigned short u16x8;

#define MFMA16(a, b, c) __builtin_amdgcn_mfma_f32_16x16x32_bf16(a, b, c, 0, 0, 0)

__device__ __forceinline__ unsigned short f2bf(float f) {
    unsigned u = __float_as_uint(f);
    return (unsigned short)((u + 0x7FFFu + ((u >> 16) & 1u)) >> 16);   // RNE
}
__device__ __forceinline__ bf16x8 negf(bf16x8 a) {
    bf16x8 r;
#pragma unroll
    for (int j = 0; j < 8; ++j) r[j] = (short)(a[j] ^ (short)0x8000);
    return r;
}

struct ClinPtrs {
    const float* xr; const float* xi;
    const float* wr; const float* wi;
    const float* br; const float* bi;
    const float* per; const float* pei;   // may be null
    void* yr; void* yi;
    int outbf;                            // 1: bf16 out, 0: fp32 out
};

// ---------------------------------------------------------------------------
// EXACT R3 complex linear (the 428.4us-total configuration; every clin
// restructure R6-R10 regressed, so this is restored verbatim, minus the
// now-unused GATE path). 512 thr = 8 waves, 128 rows/block, full 128 cols,
// grid (NROWS/128, 4). W staged bf16 in LDS once per block.
// ---------------------------------------------------------------------------
__global__ __launch_bounds__(512, 2)
void clin_proj(ClinPtrs P0, ClinPtrs P1, ClinPtrs P2, ClinPtrs P3) {
    __shared__ unsigned short wsh[2][DD][136];   // 69632 B

    const int py = blockIdx.y;
    const ClinPtrs P = (py == 0) ? P0 : (py == 1) ? P1 : (py == 2) ? P2 : P3;

    const int t = threadIdx.x;
    // ---- stage W fp32->bf16 (4096 groups of 8) ----
#pragma unroll
    for (int u = 0; u < 8; ++u) {
        const int f = t + 512 * u;
        const int c = f >> 11;
        const int rem = f & 2047;
        const int row = rem >> 4;
        const int g8 = (rem & 15) * 8;
        const float* src = (c ? P.wi : P.wr) + (long)row * DD + g8;
        const float4 a = *(const float4*)src;
        const float4 b = *(const float4*)(src + 4);
        unsigned short tmp[8] = {f2bf(a.x), f2bf(a.y), f2bf(a.z), f2bf(a.w),
                                 f2bf(b.x), f2bf(b.y), f2bf(b.z), f2bf(b.w)};
        *(u16x8*)&wsh[c][row][g8] = *(u16x8*)tmp;
    }

    const int w = t >> 6, lane = t & 63;
    const int lm = lane & 15, quad = lane >> 4;
    const long m0 = (long)blockIdx.x * 128 + w * 16;

    // ---- A fragments: rows m0+lm, k = dk*32 + quad*8 + j ----
    bf16x8 xrf[4], xif[4];
    {
        const long rbase = (m0 + lm) * DD;
#pragma unroll
        for (int dk = 0; dk < 4; ++dk) {
            const long o = rbase + dk * 32 + quad * 8;
            const float4 a0 = *(const float4*)(P.xr + o);
            const float4 a1 = *(const float4*)(P.xr + o + 4);
            const float4 b0 = *(const float4*)(P.xi + o);
            const float4 b1 = *(const float4*)(P.xi + o + 4);
            const float fr[8] = {a0.x, a0.y, a0.z, a0.w, a1.x, a1.y, a1.z, a1.w};
            const float fi[8] = {b0.x, b0.y, b0.z, b0.w, b1.x, b1.y, b1.z, b1.w};
#pragma unroll
            for (int j = 0; j < 8; ++j) {
                xrf[dk][j] = (short)f2bf(fr[j]);
                xif[dk][j] = (short)f2bf(fi[j]);
            }
        }
    }

    f32x4 Or[8], Oi[8];
    const f32x4 z = {0.f, 0.f, 0.f, 0.f};
#pragma unroll
    for (int nt = 0; nt < 8; ++nt) { Or[nt] = z; Oi[nt] = z; }

    __syncthreads();

#pragma unroll
    for (int dk = 0; dk < 4; ++dk) {
        const bf16x8 nxi = negf(xif[dk]);
        const int off = dk * 32 + quad * 8;
#pragma unroll
        for (int nt = 0; nt < 8; ++nt) {
            const bf16x8 wrf = *(bf16x8*)&wsh[0][nt * 16 + lm][off];
            const bf16x8 wif = *(bf16x8*)&wsh[1][nt * 16 + lm][off];
            Or[nt] = MFMA16(xrf[dk], wrf, Or[nt]);
            Or[nt] = MFMA16(nxi,     wif, Or[nt]);
            Oi[nt] = MFMA16(xrf[dk], wif, Oi[nt]);
            Oi[nt] = MFMA16(xif[dk], wrf, Oi[nt]);
        }
    }

    // ---- epilogue: C layout row = quad*4+reg, col = nt*16 + lm ----
#pragma unroll
    for (int nt = 0; nt < 8; ++nt) {
        const int c = nt * 16 + lm;
        const float bra = P.br[c], bia = P.bi[c];
#pragma unroll
        for (int reg = 0; reg < 4; ++reg) {
            const long R = m0 + quad * 4 + reg;
            float vr = Or[nt][reg] + bra;
            float vi = Oi[nt][reg] + bia;
            if (P.per != nullptr) {
                vr += P.per[R * DD + c];
                vi += P.pei[R * DD + c];
            }
            if (P.outbf) {
                ((unsigned short*)P.yr)[R * DD + c] = f2bf(vr);
                ((unsigned short*)P.yi)[R * DD + c] = f2bf(vi);
            } else {
                ((float*)P.yr)[R * DD + c] = vr;
                ((float*)P.yi)[R * DD + c] = vi;
            }
        }
    }
}

// ---------------------------------------------------------------------------
// Final o-projection with bf16 A (the fused gate output ga). Identical
// structure to clin_proj but the fragment build is two u16x8 loads per dk
// (no fp32->bf16, no gate product -- that moved into attn's epilogue).
// fp32 out + bias into d_out slots 0,1; reads only workspace -> no alias.
// ---------------------------------------------------------------------------
__global__ __launch_bounds__(512, 2)
void clin_obf(const unsigned short* __restrict__ xr, const unsigned short* __restrict__ xi,
              const float* __restrict__ wr, const float* __restrict__ wi,
              const float* __restrict__ br, const float* __restrict__ bi,
              float* __restrict__ yr, float* __restrict__ yi) {
    __shared__ unsigned short wsh[2][DD][136];   // 69632 B

    const int t = threadIdx.x;
#pragma unroll
    for (int u = 0; u < 8; ++u) {
        const int f = t + 512 * u;
        const int c = f >> 11;
        const int rem = f & 2047;
        const int row = rem >> 4;
        const int g8 = (rem & 15) * 8;
        const float* src = (c ? wi : wr) + (long)row * DD + g8;
        const float4 a = *(const float4*)src;
        const float4 b = *(const float4*)(src + 4);
        unsigned short tmp[8] = {f2bf(a.x), f2bf(a.y), f2bf(a.z), f2bf(a.w),
                                 f2bf(b.x), f2bf(b.y), f2bf(b.z), f2bf(b.w)};
        *(u16x8*)&wsh[c][row][g8] = *(u16x8*)tmp;
    }

    const int w = t >> 6, lane = t & 63;
    const int lm = lane & 15, quad = lane >> 4;
    const long m0 = (long)blockIdx.x * 128 + w * 16;

    // ---- A fragments: direct bf16 loads (attn Q-fragment pattern) ----
    bf16x8 xrf[4], xif[4];
    {
        const long rbase = (m0 + lm) * DD + quad * 8;
#pragma unroll
        for (int dk = 0; dk < 4; ++dk) {
            xrf[dk] = *(const bf16x8*)(xr + rbase + dk * 32);
            xif[dk] = *(const bf16x8*)(xi + rbase + dk * 32);
        }
    }

    f32x4 Or[8], Oi[8];
    const f32x4 z = {0.f, 0.f, 0.f, 0.f};
#pragma unroll
    for (int nt = 0; nt < 8; ++nt) { Or[nt] = z; Oi[nt] = z; }

    __syncthreads();

#pragma unroll
    for (int dk = 0; dk < 4; ++dk) {
        const bf16x8 nxi = negf(xif[dk]);
        const int off = dk * 32 + quad * 8;
#pragma unroll
        for (int nt = 0; nt < 8; ++nt) {
            const bf16x8 wrf = *(bf16x8*)&wsh[0][nt * 16 + lm][off];
            const bf16x8 wif = *(bf16x8*)&wsh[1][nt * 16 + lm][off];
            Or[nt] = MFMA16(xrf[dk], wrf, Or[nt]);
            Or[nt] = MFMA16(nxi,     wif, Or[nt]);
            Oi[nt] = MFMA16(xrf[dk], wif, Oi[nt]);
            Oi[nt] = MFMA16(xif[dk], wrf, Oi[nt]);
        }
    }

#pragma unroll
    for (int nt = 0; nt < 8; ++nt) {
        const int c = nt * 16 + lm;
        const float bra = br[c], bia = bi[c];
#pragma unroll
        for (int reg = 0; reg < 4; ++reg) {
            const long R = m0 + quad * 4 + reg;
            yr[R * DD + c] = Or[nt][reg] + bra;
            yi[R * DD + c] = Oi[nt][reg] + bia;
        }
    }
}

// ---------------------------------------------------------------------------
// MFMA flash attention, EXACT R3 loop (130.7 us) + fused gate epilogue:
// a = O/l is in registers; read g (fp32), write ga = f2bf(g (*) a) bf16.
// This is bit-identical to what the old gate-clin computed at fragment
// build (same op order, same rounding), so numerics are unchanged.
// ---------------------------------------------------------------------------
__global__ __launch_bounds__(512, 2)
void attn_mfma(const unsigned short* __restrict__ qr, const unsigned short* __restrict__ qi,
               const unsigned short* __restrict__ kr, const unsigned short* __restrict__ ki,
               const unsigned short* __restrict__ vr, const unsigned short* __restrict__ vi,
               const float* __restrict__ g_r, const float* __restrict__ g_i,
               unsigned short* __restrict__ gar, unsigned short* __restrict__ gai) {
    __shared__ unsigned short ks[2][2][32][136];   // 34816 B
    __shared__ unsigned short vt[2][2][DD][40];    // 40960 B
    __shared__ unsigned short ps[128][40];         // 10240 B

    const int t = threadIdx.x;
    const int w = t >> 6, lane = t & 63;
    const int lm = lane & 15, quad = lane >> 4;

    const int bid = blockIdx.x;
    const int xcd = bid & 7;
    const int rr = bid >> 3;          // 0..31
    const int qt = rr & 15;
    const int h  = xcd + 8 * (rr >> 4);
    const long hbase = (long)h * SS * DD;
    const int q0 = qt * 128;
    const float scale = 0.08838834764831845f;   // 128^-0.5

    int kC[2], kR[2], kG[2];
    const unsigned short* kp[2];
#pragma unroll
    for (int u = 0; u < 2; ++u) {
        const int f = t + 512 * u;
        kC[u] = f >> 9;
        kR[u] = (f & 511) >> 4;
        kG[u] = (f & 15) * 8;
        kp[u] = (kC[u] ? ki : kr) + hbase + (long)kR[u] * DD + kG[u];
    }
    const int vC = t >> 8;
    const int vS2 = (t & 15) * 2;
    const int vD8 = ((t >> 4) & 15) * 8;
    const unsigned short* vp = (vC ? vi : vr) + hbase + (long)vS2 * DD + vD8;

    u16x8 kA0, kA1, vA0, vA1;
    kA0 = *(const u16x8*)(kp[0]);
    kA1 = *(const u16x8*)(kp[1]);
    vA0 = *(const u16x8*)(vp);
    vA1 = *(const u16x8*)(vp + DD);

    bf16x8 qrf[4], qif[4];
    {
        const long rb = hbase + (long)(q0 + w * 16 + lm) * DD;
#pragma unroll
        for (int dk = 0; dk < 4; ++dk) {
            qrf[dk] = *(const bf16x8*)(qr + rb + dk * 32 + quad * 8);
            qif[dk] = *(const bf16x8*)(qi + rb + dk * 32 + quad * 8);
        }
    }

    f32x4 Or[8], Oi[8];
    const f32x4 z = {0.f, 0.f, 0.f, 0.f};
#pragma unroll
    for (int nt = 0; nt < 8; ++nt) { Or[nt] = z; Oi[nt] = z; }
    float l_st[4] = {0.f, 0.f, 0.f, 0.f};

#pragma unroll
    for (int u = 0; u < 2; ++u)
        *(u16x8*)&ks[0][kC[u]][kR[u]][kG[u]] = (u ? kA1 : kA0);
#pragma unroll
    for (int j = 0; j < 8; ++j) {
        const unsigned val = (unsigned)(unsigned short)vA0[j] |
                             ((unsigned)(unsigned short)vA1[j] << 16);
        *(unsigned*)&vt[0][vC][vD8 + j][vS2] = val;
    }
    __syncthreads();

    for (int kt = 0; kt < SS / 32; ++kt) {
        const int b = kt & 1;
        if (kt + 1 < SS / 32) {
            const long koff = (long)(kt + 1) * 32 * DD;
            kA0 = *(const u16x8*)(kp[0] + koff);
            kA1 = *(const u16x8*)(kp[1] + koff);
            vA0 = *(const u16x8*)(vp + koff);
            vA1 = *(const u16x8*)(vp + koff + DD);
        }

        f32x4 sr0 = z, sr1 = z, si0 = z, si1 = z;
#pragma unroll
        for (int dk = 0; dk < 4; ++dk) {
            const int off = dk * 32 + quad * 8;
            const bf16x8 kr0 = *(bf16x8*)&ks[b][0][lm][off];
            const bf16x8 ki0 = *(bf16x8*)&ks[b][1][lm][off];
            const bf16x8 kr1 = *(bf16x8*)&ks[b][0][16 + lm][off];
            const bf16x8 ki1 = *(bf16x8*)&ks[b][1][16 + lm][off];
            const bf16x8 nq = negf(qrf[dk]);
            sr0 = MFMA16(qrf[dk], kr0, sr0);  sr0 = MFMA16(qif[dk], ki0, sr0);
            si0 = MFMA16(qif[dk], kr0, si0);  si0 = MFMA16(nq, ki0, si0);
            sr1 = MFMA16(qrf[dk], kr1, sr1);  sr1 = MFMA16(qif[dk], ki1, sr1);
            si1 = MFMA16(qif[dk], kr1, si1);  si1 = MFMA16(nq, ki1, si1);
        }

#pragma unroll
        for (int reg = 0; reg < 4; ++reg) {
            const float s0 = __builtin_amdgcn_sqrtf(
                fmaf(sr0[reg], sr0[reg], fmaf(si0[reg], si0[reg], 1e-8f))) * scale;
            const float s1 = __builtin_amdgcn_sqrtf(
                fmaf(sr1[reg], sr1[reg], fmaf(si1[reg], si1[reg], 1e-8f))) * scale;
            const float p0 = __expf(s0);
            const float p1 = __expf(s1);
            l_st[reg] += p0 + p1;
            ps[w * 16 + quad * 4 + reg][lm]      = f2bf(p0);
            ps[w * 16 + quad * 4 + reg][16 + lm] = f2bf(p1);
        }

        const bf16x8 pf = *(bf16x8*)&ps[w * 16 + lm][quad * 8];
#pragma unroll
        for (int nt = 0; nt < 8; ++nt) {
            const bf16x8 vrf = *(bf16x8*)&vt[b][0][nt * 16 + lm][quad * 8];
            const bf16x8 vif = *(bf16x8*)&vt[b][1][nt * 16 + lm][quad * 8];
            Or[nt] = MFMA16(pf, vrf, Or[nt]);
            Oi[nt] = MFMA16(pf, vif, Oi[nt]);
        }

        if (kt + 1 < SS / 32) {
            __syncthreads();
#pragma unroll
            for (int u = 0; u < 2; ++u)
                *(u16x8*)&ks[b ^ 1][kC[u]][kR[u]][kG[u]] = (u ? kA1 : kA0);
#pragma unroll
            for (int j = 0; j < 8; ++j) {
                const unsigned val = (unsigned)(unsigned short)vA0[j] |
                                     ((unsigned)(unsigned short)vA1[j] << 16);
                *(unsigned*)&vt[b ^ 1][vC][vD8 + j][vS2] = val;
            }
            __syncthreads();
        }
    }

    // ---- finalize + fused gate: ga = f2bf(g (*) (O/l)) ----
    float linv[4];
#pragma unroll
    for (int reg = 0; reg < 4; ++reg) {
        float l = l_st[reg];
#pragma unroll
        for (int off = 1; off < 16; off <<= 1) l += __shfl_xor(l, off);
        linv[reg] = 1.f / l;
    }
    const long ob = hbase + (long)(q0 + w * 16) * DD;
#pragma unroll
    for (int nt = 0; nt < 8; ++nt) {
        const int c = nt * 16 + lm;
#pragma unroll
        for (int reg = 0; reg < 4; ++reg) {
            const long R = ob + (long)(quad * 4 + reg) * DD + c;
            const float ar = Or[nt][reg] * linv[reg];
            const float ai = Oi[nt][reg] * linv[reg];
            const float g1 = g_r[R];
            const float g2 = g_i[R];
            gar[R] = f2bf(g1 * ar - g2 * ai);
            gai[R] = f2bf(g1 * ai + g2 * ar);
        }
    }
}

// ---------------------------------------------------------------------------
extern "C" void kernel_launch(void* const* d_in, const int* in_sizes, int n_in,
                              void* d_out, int out_size, void* d_ws, size_t ws_size,
                              hipStream_t stream) {
    const float* q_r    = (const float*)d_in[0];
    const float* q_i    = (const float*)d_in[1];
    const float* k_r    = (const float*)d_in[2];
    const float* k_i    = (const float*)d_in[3];
    const float* v_r    = (const float*)d_in[4];
    const float* v_i    = (const float*)d_in[5];
    const float* pe_q_r = (const float*)d_in[6];
    const float* pe_q_i = (const float*)d_in[7];
    const float* pe_k_r = (const float*)d_in[8];
    const float* pe_k_i = (const float*)d_in[9];
    const float* qw_r = (const float*)d_in[10];
    const float* qw_i = (const float*)d_in[11];
    const float* qb_r = (const float*)d_in[12];
    const float* qb_i = (const float*)d_in[13];
    const float* kw_r = (const float*)d_in[14];
    const float* kw_i = (const float*)d_in[15];
    const float* kb_r = (const float*)d_in[16];
    const float* kb_i = (const float*)d_in[17];
    const float* vw_r = (const float*)d_in[18];
    const float* vw_i = (const float*)d_in[19];
    const float* vb_r = (const float*)d_in[20];
    const float* vb_i = (const float*)d_in[21];
    const float* gw_r = (const float*)d_in[22];
    const float* gw_i = (const float*)d_in[23];
    const float* gb_r = (const float*)d_in[24];
    const float* gb_i = (const float*)d_in[25];
    const float* ow_r = (const float*)d_in[26];
    const float* ow_i = (const float*)d_in[27];
    const float* ob_r = (const float*)d_in[28];
    const float* ob_i = (const float*)d_in[29];

    float* out_r = (float*)d_out;              // final out_r
    float* out_i = out_r + (long)OUTSZ;
    float* g_r   = out_r + 2L * OUTSZ;         // gate outputs (returned)
    float* g_i   = out_r + 3L * OUTSZ;

    unsigned short* ws = (unsigned short*)d_ws; // 8 x 8 MiB bf16 = 64 MiB
    unsigned short* pqr = ws + 0L * OUTSZ;
    unsigned short* pqi = ws + 1L * OUTSZ;
    unsigned short* pkr = ws + 2L * OUTSZ;
    unsigned short* pki = ws + 3L * OUTSZ;
    unsigned short* pvr = ws + 4L * OUTSZ;
    unsigned short* pvi = ws + 5L * OUTSZ;
    unsigned short* gar = ws + 6L * OUTSZ;      // fused gate output (bf16)
    unsigned short* gai = ws + 7L * OUTSZ;

    const dim3 blk(512);

    ClinPtrs P0 = {q_r, q_i, qw_r, qw_i, qb_r, qb_i, pe_q_r, pe_q_i, pqr, pqi, 1};
    ClinPtrs P1 = {k_r, k_i, kw_r, kw_i, kb_r, kb_i, pe_k_r, pe_k_i, pkr, pki, 1};
    ClinPtrs P2 = {v_r, v_i, vw_r, vw_i, vb_r, vb_i, nullptr, nullptr, pvr, pvi, 1};
    ClinPtrs P3 = {q_r, q_i, gw_r, gw_i, gb_r, gb_i, nullptr, nullptr, g_r, g_i, 0};

    // all 4 projections in one launch: grid (256 row-blocks, 4 projections)
    // -- exact R3 kernel and config (best measured)
    clin_proj<<<dim3(NROWS / 128, 4), blk, 0, stream>>>(P0, P1, P2, P3);

    // flash attention (exact R3 loop) + fused gate epilogue -> ga bf16 in ws
    attn_mfma<<<dim3((SS / 128) * HH), blk, 0, stream>>>(
        pqr, pqi, pkr, pki, pvr, pvi, g_r, g_i, gar, gai);

    // final o-projection: plain bf16-A clin, fp32 out into d_out slots 0,1
    clin_obf<<<dim3(NROWS / 128), blk, 0, stream>>>(
        gar, gai, ow_r, ow_i, ob_r, ob_i, out_r, out_i);
}